// Round 7
// baseline (31.941 us; speedup 1.0000x reference)
//
#include <hip/hip_runtime.h>
#include <math.h>

#define TLEN 1024

typedef int i32x2 __attribute__((ext_vector_type(2)));

__device__ __forceinline__ float2 cadd(float2 a, float2 b){ return make_float2(a.x+b.x, a.y+b.y); }
__device__ __forceinline__ float2 csub(float2 a, float2 b){ return make_float2(a.x-b.x, a.y-b.y); }
__device__ __forceinline__ float2 cmul(float2 a, float2 b){
    return make_float2(fmaf(a.x, b.x, -(a.y*b.y)), fmaf(a.x, b.y, a.y*b.x));
}
__device__ __forceinline__ float2 cmulnegi(float2 a){ return make_float2(a.y, -a.x); } // a * (-i)
__device__ __forceinline__ int bitrev6(int l){
    return ((l & 1) << 5) | ((l & 2) << 3) | ((l & 4) << 1)
         | ((l & 8) >> 1) | ((l & 16) >> 3) | ((l & 32) >> 5);
}

// ---- cross-lane partner primitives (verified R4) ----
#define DPP_XOR1  0xB1   // quad_perm [1,0,3,2]
#define DPP_XOR2  0x4E   // quad_perm [2,3,0,1]
#define DPP_XOR8  0x128  // row_ror:8
#define SWZ_XOR4  0x101F // bitmode xor=4
#define SWZ_XOR16 0x401F // bitmode xor=16

template<int CTRL>
__device__ __forceinline__ float2 dpp2(float2 v){
    return make_float2(
        __int_as_float(__builtin_amdgcn_mov_dpp(__float_as_int(v.x), CTRL, 0xF, 0xF, false)),
        __int_as_float(__builtin_amdgcn_mov_dpp(__float_as_int(v.y), CTRL, 0xF, 0xF, false)));
}
template<int PAT>
__device__ __forceinline__ float2 swz2(float2 v){
    return make_float2(
        __int_as_float(__builtin_amdgcn_ds_swizzle(__float_as_int(v.x), PAT)),
        __int_as_float(__builtin_amdgcn_ds_swizzle(__float_as_int(v.y), PAT)));
}
__device__ __forceinline__ float p32f(float v, bool up){
#if __has_builtin(__builtin_amdgcn_permlane32_swap)
    i32x2 r = __builtin_amdgcn_permlane32_swap(__float_as_int(v), __float_as_int(v), false, false);
    return __int_as_float(up ? r[0] : r[1]);
#else
    int a = __float_as_int(v), b = __float_as_int(v);
    asm("v_permlane32_swap_b32 %0, %1" : "+v"(a), "+v"(b));
    return __int_as_float(up ? a : b);
#endif
}
__device__ __forceinline__ float2 p32_2(float2 v, bool up){
    return make_float2(p32f(v.x, up), p32f(v.y, up));
}

// DFT-4 (radix-2x2)
__device__ __forceinline__ void dft4(float2 x0, float2 x1, float2 x2, float2 x3,
                                     float2& y0, float2& y1, float2& y2, float2& y3){
    float2 t0 = cadd(x0, x2);
    float2 t1 = csub(x0, x2);
    float2 t2 = cadd(x1, x3);
    float2 t3 = csub(x1, x3);
    float2 n3 = cmulnegi(t3);
    y0 = cadd(t0, t2);
    y2 = csub(t0, t2);
    y1 = cadd(t1, n3);
    y3 = csub(t1, n3);
}

// in-lane 16-point DFT, natural in -> natural out (verified R4)
__device__ __forceinline__ void fft16(float2 z[16]){
    const float C1 = 0.92387953251128675613f, S1 = 0.38268343236508977173f;
    const float H  = 0.70710678118654752440f;
    const float2 W1 = make_float2( C1, -S1);
    const float2 W2 = make_float2(  H,  -H);
    const float2 W3 = make_float2( S1, -C1);
    const float2 W6 = make_float2( -H,  -H);
    const float2 W9 = make_float2(-C1,  S1);

    float2 A0[4], A1[4], A2[4], A3[4];
    #pragma unroll
    for (int b = 0; b < 4; ++b)
        dft4(z[b], z[4+b], z[8+b], z[12+b], A0[b], A1[b], A2[b], A3[b]);

    A1[1] = cmul(A1[1], W1);  A1[2] = cmul(A1[2], W2);  A1[3] = cmul(A1[3], W3);
    A2[1] = cmul(A2[1], W2);  A2[2] = cmulnegi(A2[2]);  A2[3] = cmul(A2[3], W6);
    A3[1] = cmul(A3[1], W3);  A3[2] = cmul(A3[2], W6);  A3[3] = cmul(A3[3], W9);

    dft4(A0[0], A0[1], A0[2], A0[3], z[0], z[4], z[8],  z[12]);
    dft4(A1[0], A1[1], A1[2], A1[3], z[1], z[5], z[9],  z[13]);
    dft4(A2[0], A2[1], A2[2], A2[3], z[2], z[6], z[10], z[14]);
    dft4(A3[0], A3[1], A3[2], A3[3], z[3], z[7], z[11], z[15]);
}

template<bool TW, typename F>
__device__ __forceinline__ void dif_stage(float2 z[16], F partner, float sg, float2 w){
    #pragma unroll
    for (int r = 0; r < 16; ++r){
        float2 o = partner(z[r]);
        float2 pre = make_float2(fmaf(sg, z[r].x, o.x), fmaf(sg, z[r].y, o.y));
        z[r] = TW ? cmul(pre, w) : pre;
    }
}
template<bool TW, typename F>
__device__ __forceinline__ void dit_stage(float2 z[16], F partner, float sg, float2 w){
    #pragma unroll
    for (int r = 0; r < 16; ++r){
        float2 zz = TW ? cmul(z[r], w) : z[r];
        float2 o = partner(zz);
        z[r] = make_float2(fmaf(sg, zz.x, o.x), fmaf(sg, zz.y, o.y));
    }
}

// cross-lane DIF FFT-64: natural in -> bit-reversed out (verified R4)
__device__ __forceinline__ void xfft_dif(float2 z[16], const float2 Wt[5], int lane){
    const float2 ONE = make_float2(1.0f, 0.0f);
    {   const bool up = (lane & 32) != 0; const float sg = up ? -1.0f : 1.0f;
        dif_stage<true>(z, [&](float2 v){ return p32_2(v, up); }, sg, up ? Wt[4] : ONE); }
    {   const bool up = (lane & 16) != 0; const float sg = up ? -1.0f : 1.0f;
        dif_stage<true>(z, [](float2 v){ return swz2<SWZ_XOR16>(v); }, sg, up ? Wt[3] : ONE); }
    {   const bool up = (lane & 8) != 0;  const float sg = up ? -1.0f : 1.0f;
        dif_stage<true>(z, [](float2 v){ return dpp2<DPP_XOR8>(v); }, sg, up ? Wt[2] : ONE); }
    {   const bool up = (lane & 4) != 0;  const float sg = up ? -1.0f : 1.0f;
        dif_stage<true>(z, [](float2 v){ return swz2<SWZ_XOR4>(v); }, sg, up ? Wt[1] : ONE); }
    {   const bool up = (lane & 2) != 0;  const float sg = up ? -1.0f : 1.0f;
        dif_stage<true>(z, [](float2 v){ return dpp2<DPP_XOR2>(v); }, sg, up ? Wt[0] : ONE); }
    {   const float sg = (lane & 1) ? -1.0f : 1.0f;
        dif_stage<false>(z, [](float2 v){ return dpp2<DPP_XOR1>(v); }, sg, ONE); }
}

// cross-lane DIT FFT-64: bit-reversed in -> natural out (verified R4)
__device__ __forceinline__ void xfft_dit(float2 z[16], const float2 Wt[5], int lane){
    const float2 ONE = make_float2(1.0f, 0.0f);
    {   const float sg = (lane & 1) ? -1.0f : 1.0f;
        dit_stage<false>(z, [](float2 v){ return dpp2<DPP_XOR1>(v); }, sg, ONE); }
    {   const bool up = (lane & 2) != 0;  const float sg = up ? -1.0f : 1.0f;
        dit_stage<true>(z, [](float2 v){ return dpp2<DPP_XOR2>(v); }, sg, up ? Wt[0] : ONE); }
    {   const bool up = (lane & 4) != 0;  const float sg = up ? -1.0f : 1.0f;
        dit_stage<true>(z, [](float2 v){ return swz2<SWZ_XOR4>(v); }, sg, up ? Wt[1] : ONE); }
    {   const bool up = (lane & 8) != 0;  const float sg = up ? -1.0f : 1.0f;
        dit_stage<true>(z, [](float2 v){ return dpp2<DPP_XOR8>(v); }, sg, up ? Wt[2] : ONE); }
    {   const bool up = (lane & 16) != 0; const float sg = up ? -1.0f : 1.0f;
        dit_stage<true>(z, [](float2 v){ return swz2<SWZ_XOR16>(v); }, sg, up ? Wt[3] : ONE); }
    {   const bool up = (lane & 32) != 0; const float sg = up ? -1.0f : 1.0f;
        dit_stage<true>(z, [&](float2 v){ return p32_2(v, up); }, sg, up ? Wt[4] : ONE); }
}

// ============================================================================
// prep v2: a = (D_0 M F)(D_1 M F)...(D_5 M F) e_0 — weights only.
// Phase 1 (1024 threads): phasors + wmid -> LDS.  Phase 2 (wave 0, ZERO
// barriers): 6-layer chain on the R4 single-wave FFT datapath, reversed order
// (v = F v; v = M v; v = D_l v for l = 5..0). All positive scales dropped.
// ============================================================================
__global__ __launch_bounds__(1024)
void prep_kernel(const float* __restrict__ W, float2* __restrict__ a_out)
{
    __shared__ float2 ph[6 * TLEN];   // exp(i*W[l][t])        48 KiB
    __shared__ float2 wm[TLEN];       // wmid[lane][r]          8 KiB

    const int tid = threadIdx.x;

    // ---- phase 1 ----
    #pragma unroll
    for (int i = tid; i < 6 * TLEN; i += 1024){
        float sv, cv; sincosf(W[i], &sv, &cv);
        ph[i] = make_float2(cv, sv);
    }
    {
        int l = tid >> 4, r = tid & 15;
        int cb = bitrev6(l & 63);
        if (tid < TLEN){
            float sv, cv;
            sincosf(-6.28318530717958647692f * (float)(cb * r) / 1024.0f, &sv, &cv);
            wm[tid] = make_float2(cv, sv);
        }
    }
    __syncthreads();

    // ---- phase 2: wave 0 only, no further barriers ----
    if (tid >= 64) return;
    const int lane = tid;
    const int c = bitrev6(lane);

    float2 Wt[5];
    #pragma unroll
    for (int k = 0; k < 5; ++k){
        const int h = 2 << k;
        float sv, cv;
        sincosf(-3.14159265358979323846f * (float)(lane & (h - 1)) / (float)h, &sv, &cv);
        Wt[k] = make_float2(cv, sv);
    }

    float2 z[16];
    #pragma unroll
    for (int r = 0; r < 16; ++r)
        z[r] = make_float2((lane == 0 && r == 0) ? 1.0f : 0.0f, 0.0f);

    auto midtw = [&](){
        #pragma unroll
        for (int r = 0; r < 16; ++r) z[r] = cmul(z[r], wm[lane * 16 + r]);
    };

    #pragma unroll
    for (int lp = 0; lp < 3; ++lp){
        const int lA = 5 - 2 * lp;     // 5, 3, 1  (strided-layout M, D)
        const int lB = 4 - 2 * lp;     // 4, 2, 0  (consecutive-layout M, D)

        // ---- v = F v : DFT-A (consecutive -> strided-bitrev) ----
        xfft_dif(z, Wt, lane);
        midtw();
        fft16(z);
        // ---- v = M v (strided: partner lane^32, sign = lane bit5) ----
        {
            const bool upm = (lane & 32) != 0;
            const float sgm = upm ? -1.0f : 1.0f;
            #pragma unroll
            for (int r = 0; r < 16; ++r){
                float2 o = p32_2(z[r], upm);
                z[r] = make_float2(fmaf(sgm, z[r].x, o.x), fmaf(sgm, z[r].y, o.y));
            }
        }
        // ---- v = D_lA v (strided: t = 64r + c) ----
        #pragma unroll
        for (int r = 0; r < 16; ++r) z[r] = cmul(z[r], ph[lA * TLEN + (r << 6) + c]);

        // ---- v = F v : DFT-B (strided-bitrev -> consecutive) ----
        fft16(z);
        midtw();
        xfft_dit(z, Wt, lane);
        // ---- v = M v (consecutive: adjacent regs) ----
        #pragma unroll
        for (int m = 0; m < 8; ++m){
            float2 a = z[2*m], b = z[2*m+1];
            z[2*m]   = cadd(a, b);
            z[2*m+1] = csub(a, b);
        }
        // ---- v = D_lB v (consecutive: t = 16*lane + r) ----
        #pragma unroll
        for (int r = 0; r < 16; ++r) z[r] = cmul(z[r], ph[lB * TLEN + lane * 16 + r]);
    }

    // a in consecutive layout
    #pragma unroll
    for (int r = 0; r < 16; ++r) a_out[lane * 16 + r] = z[r];
}

// ============================================================================
// dot: out[row] = (sin(angle(a . z_row)) + 1)/2,  z_t = (sqrt(1-x^2), x)
// ============================================================================
__global__ __launch_bounds__(256)
void dot_kernel(const float* __restrict__ X,
                const float2* __restrict__ a,
                float* __restrict__ out)
{
    const int lane = threadIdx.x & 63;
    const int row  = blockIdx.x * 4 + (threadIdx.x >> 6);

    const float4* px = (const float4*)(X + (size_t)row * TLEN + lane * 16);
    const float4* pa = (const float4*)(a + lane * 16);   // 16 float2 = 8 float4

    float re = 0.0f, im = 0.0f;
    #pragma unroll
    for (int i = 0; i < 4; ++i){
        float4 xv = px[i];
        float4 qa = pa[2*i];
        float4 qb = pa[2*i + 1];
        float xs[4] = {xv.x, xv.y, xv.z, xv.w};
        float ar[4] = {qa.x, qa.z, qb.x, qb.z};
        float ai[4] = {qa.y, qa.w, qb.y, qb.w};
        #pragma unroll
        for (int j = 0; j < 4; ++j){
            float x  = fminf(fmaxf(xs[j], -0.999f), 0.999f);
            float cc = sqrtf(fmaf(-x, x, 1.0f));
            re = fmaf(ar[j], cc, re);  re = fmaf(-ai[j], x,  re);
            im = fmaf(ar[j], x,  im);  im = fmaf( ai[j], cc, im);
        }
    }

    float2 s = make_float2(re, im);
    s = cadd(s, dpp2<DPP_XOR1>(s));
    s = cadd(s, dpp2<DPP_XOR2>(s));
    s = cadd(s, swz2<SWZ_XOR4>(s));
    s = cadd(s, dpp2<DPP_XOR8>(s));
    s = cadd(s, swz2<SWZ_XOR16>(s));
    s = cadd(s, p32_2(s, (lane & 32) != 0));

    if (lane == 0){
        out[row] = fmaf(s.y * rsqrtf(fmaf(s.x, s.x, s.y * s.y)), 0.5f, 0.5f);
    }
}

extern "C" void kernel_launch(void* const* d_in, const int* in_sizes, int n_in,
                              void* d_out, int out_size, void* d_ws, size_t ws_size,
                              hipStream_t stream) {
    const float* X = (const float*)d_in[0];   // [4096, 1024]
    const float* W = (const float*)d_in[1];   // [6*1024]
    float* out = (float*)d_out;               // [4096]
    (void)in_sizes; (void)n_in; (void)out_size; (void)ws_size;

    float2* aW = (float2*)d_ws;               // 8 KiB of workspace

    prep_kernel<<<1, 1024, 0, stream>>>(W, aW);
    dot_kernel<<<4096 / 4, 256, 0, stream>>>(X, aW, out);
}

// Round 8
// 20.557 us; speedup vs baseline: 1.5538x; 1.5538x over previous
//
#include <hip/hip_runtime.h>
#include <math.h>

#define TLEN 1024

typedef int i32x2 __attribute__((ext_vector_type(2)));

__device__ __forceinline__ float2 cadd(float2 a, float2 b){ return make_float2(a.x+b.x, a.y+b.y); }
__device__ __forceinline__ float2 csub(float2 a, float2 b){ return make_float2(a.x-b.x, a.y-b.y); }
__device__ __forceinline__ float2 cmul(float2 a, float2 b){
    return make_float2(fmaf(a.x, b.x, -(a.y*b.y)), fmaf(a.x, b.y, a.y*b.x));
}
__device__ __forceinline__ float2 cmulnegi(float2 a){ return make_float2(a.y, -a.x); }  // a * (-i)
__device__ __forceinline__ float2 cmulposi(float2 a){ return make_float2(-a.y, a.x); }  // a * (+i)
__device__ __forceinline__ int bitrev6(int l){
    return ((l & 1) << 5) | ((l & 2) << 3) | ((l & 4) << 1)
         | ((l & 8) >> 1) | ((l & 16) >> 3) | ((l & 32) >> 5);
}

// ---- cross-lane partner primitives (verified R4) ----
#define DPP_XOR1  0xB1   // quad_perm [1,0,3,2]
#define DPP_XOR2  0x4E   // quad_perm [2,3,0,1]
#define DPP_XOR8  0x128  // row_ror:8
#define SWZ_XOR4  0x101F // bitmode xor=4
#define SWZ_XOR16 0x401F // bitmode xor=16

template<int CTRL>
__device__ __forceinline__ float2 dpp2(float2 v){
    return make_float2(
        __int_as_float(__builtin_amdgcn_mov_dpp(__float_as_int(v.x), CTRL, 0xF, 0xF, false)),
        __int_as_float(__builtin_amdgcn_mov_dpp(__float_as_int(v.y), CTRL, 0xF, 0xF, false)));
}
template<int PAT>
__device__ __forceinline__ float2 swz2(float2 v){
    return make_float2(
        __int_as_float(__builtin_amdgcn_ds_swizzle(__float_as_int(v.x), PAT)),
        __int_as_float(__builtin_amdgcn_ds_swizzle(__float_as_int(v.y), PAT)));
}
__device__ __forceinline__ float p32f(float v, bool up){
#if __has_builtin(__builtin_amdgcn_permlane32_swap)
    i32x2 r = __builtin_amdgcn_permlane32_swap(__float_as_int(v), __float_as_int(v), false, false);
    return __int_as_float(up ? r[0] : r[1]);
#else
    int a = __float_as_int(v), b = __float_as_int(v);
    asm("v_permlane32_swap_b32 %0, %1" : "+v"(a), "+v"(b));
    return __int_as_float(up ? a : b);
#endif
}
__device__ __forceinline__ float2 p32_2(float2 v, bool up){
    return make_float2(p32f(v.x, up), p32f(v.y, up));
}

// DFT-4: y_k = sum_a x_a W4^{ak}
__device__ __forceinline__ void dft4(float2 x0, float2 x1, float2 x2, float2 x3,
                                     float2& y0, float2& y1, float2& y2, float2& y3){
    float2 t0 = cadd(x0, x2);
    float2 t1 = csub(x0, x2);
    float2 t2 = cadd(x1, x3);
    float2 t3 = csub(x1, x3);
    float2 n3 = cmulnegi(t3);
    y0 = cadd(t0, t2);
    y2 = csub(t0, t2);
    y1 = cadd(t1, n3);
    y3 = csub(t1, n3);
}

// selected output k of DFT-4 (k = wave-uniform)
__device__ __forceinline__ float2 combine4(float2 x0, float2 x1, float2 x2, float2 x3, int k){
    float2 e = cadd(x0, x2), f = csub(x0, x2);
    float2 g = cadd(x1, x3), h = csub(x1, x3);
    if (k == 0) return cadd(e, g);
    if (k == 1) return cadd(f, cmulnegi(h));
    if (k == 2) return csub(e, g);
    return cadd(f, cmulposi(h));
}

// u[j] *= W16^{j*e}, e wave-uniform in [0,4)
__device__ __forceinline__ void tw16(float2 u[4], int e){
    const float C1 = 0.92387953251128675613f, S1 = 0.38268343236508977173f;
    const float H  = 0.70710678118654752440f;
    if (e == 1){
        u[1] = cmul(u[1], make_float2( C1, -S1));
        u[2] = cmul(u[2], make_float2(  H,  -H));
        u[3] = cmul(u[3], make_float2( S1, -C1));
    } else if (e == 2){
        u[1] = cmul(u[1], make_float2(  H,  -H));
        u[2] = cmulnegi(u[2]);
        u[3] = cmul(u[3], make_float2( -H,  -H));
    } else if (e == 3){
        u[1] = cmul(u[1], make_float2( S1, -C1));
        u[2] = cmul(u[2], make_float2( -H,  -H));
        u[3] = cmul(u[3], make_float2(-C1,  S1));
    }
}

// ---- cross-lane FFT-64 over lanes, 4 regs (verified structure R4) ----
template<bool TW, typename F>
__device__ __forceinline__ void dif_stage4(float2 z[4], F partner, float sg, float2 w){
    #pragma unroll
    for (int r = 0; r < 4; ++r){
        float2 o = partner(z[r]);
        float2 pre = make_float2(fmaf(sg, z[r].x, o.x), fmaf(sg, z[r].y, o.y));
        z[r] = TW ? cmul(pre, w) : pre;
    }
}
template<bool TW, typename F>
__device__ __forceinline__ void dit_stage4(float2 z[4], F partner, float sg, float2 w){
    #pragma unroll
    for (int r = 0; r < 4; ++r){
        float2 zz = TW ? cmul(z[r], w) : z[r];
        float2 o = partner(zz);
        z[r] = make_float2(fmaf(sg, zz.x, o.x), fmaf(sg, zz.y, o.y));
    }
}
__device__ __forceinline__ void xfft_dif4(float2 z[4], const float2 Wt[5], int lane){
    const float2 ONE = make_float2(1.0f, 0.0f);
    {   const bool up = (lane & 32) != 0; const float sg = up ? -1.0f : 1.0f;
        dif_stage4<true>(z, [&](float2 v){ return p32_2(v, up); }, sg, up ? Wt[4] : ONE); }
    {   const bool up = (lane & 16) != 0; const float sg = up ? -1.0f : 1.0f;
        dif_stage4<true>(z, [](float2 v){ return swz2<SWZ_XOR16>(v); }, sg, up ? Wt[3] : ONE); }
    {   const bool up = (lane & 8) != 0;  const float sg = up ? -1.0f : 1.0f;
        dif_stage4<true>(z, [](float2 v){ return dpp2<DPP_XOR8>(v); }, sg, up ? Wt[2] : ONE); }
    {   const bool up = (lane & 4) != 0;  const float sg = up ? -1.0f : 1.0f;
        dif_stage4<true>(z, [](float2 v){ return swz2<SWZ_XOR4>(v); }, sg, up ? Wt[1] : ONE); }
    {   const bool up = (lane & 2) != 0;  const float sg = up ? -1.0f : 1.0f;
        dif_stage4<true>(z, [](float2 v){ return dpp2<DPP_XOR2>(v); }, sg, up ? Wt[0] : ONE); }
    {   const float sg = (lane & 1) ? -1.0f : 1.0f;
        dif_stage4<false>(z, [](float2 v){ return dpp2<DPP_XOR1>(v); }, sg, ONE); }
}
__device__ __forceinline__ void xfft_dit4(float2 z[4], const float2 Wt[5], int lane){
    const float2 ONE = make_float2(1.0f, 0.0f);
    {   const float sg = (lane & 1) ? -1.0f : 1.0f;
        dit_stage4<false>(z, [](float2 v){ return dpp2<DPP_XOR1>(v); }, sg, ONE); }
    {   const bool up = (lane & 2) != 0;  const float sg = up ? -1.0f : 1.0f;
        dit_stage4<true>(z, [](float2 v){ return dpp2<DPP_XOR2>(v); }, sg, up ? Wt[0] : ONE); }
    {   const bool up = (lane & 4) != 0;  const float sg = up ? -1.0f : 1.0f;
        dit_stage4<true>(z, [](float2 v){ return swz2<SWZ_XOR4>(v); }, sg, up ? Wt[1] : ONE); }
    {   const bool up = (lane & 8) != 0;  const float sg = up ? -1.0f : 1.0f;
        dit_stage4<true>(z, [](float2 v){ return dpp2<DPP_XOR8>(v); }, sg, up ? Wt[2] : ONE); }
    {   const bool up = (lane & 16) != 0; const float sg = up ? -1.0f : 1.0f;
        dit_stage4<true>(z, [](float2 v){ return swz2<SWZ_XOR16>(v); }, sg, up ? Wt[3] : ONE); }
    {   const bool up = (lane & 32) != 0; const float sg = up ? -1.0f : 1.0f;
        dit_stage4<true>(z, [&](float2 v){ return p32_2(v, up); }, sg, up ? Wt[4] : ONE); }
}

// ============================================================================
// prep v3: a = (D_0 M F)(D_1 M F)...(D_5 M F) e_0, 4 waves (one per SIMD).
// 16 regs split as r = 4*wid + j. FFT-16-over-r = FFT-4(cross-wave, LDS
// exchange) x FFT-4(in-reg) with W16 twiddles. First F skipped (F e0 uniform).
// 10 barriers total. Phasors via __sincosf on the fly (accuracy OK per R4).
// ============================================================================
__global__ __launch_bounds__(256)
void prep_kernel(const float* __restrict__ W, float2* __restrict__ a_out)
{
    __shared__ float2 xbuf[16 * 64];   // 8 KiB exchange

    const int lane = threadIdx.x & 63;
    const int wid  = threadIdx.x >> 6;   // 0..3
    const int c = bitrev6(lane);

    float2 Wt[5];
    #pragma unroll
    for (int k = 0; k < 5; ++k){
        const int h = 2 << k;
        float sv, cv;
        sincosf(-3.14159265358979323846f * (float)(lane & (h - 1)) / (float)h, &sv, &cv);
        Wt[k] = make_float2(cv, sv);
    }
    // mid twiddles wmv[j] = W1024^{c*(4*wid+j)} = base * step^j
    float2 wmv[4];
    {
        const float theta = -6.28318530717958647692f * (float)c / 1024.0f;
        float sv, cv;
        __sincosf(theta * (float)(4 * wid), &sv, &cv); float2 base = make_float2(cv, sv);
        __sincosf(theta, &sv, &cv);                    float2 step = make_float2(cv, sv);
        wmv[0] = base;
        wmv[1] = cmul(wmv[0], step);
        wmv[2] = cmul(wmv[1], step);
        wmv[3] = cmul(wmv[2], step);
    }

    float2 z[4];
    #pragma unroll
    for (int j = 0; j < 4; ++j) z[j] = make_float2(1.0f, 0.0f);  // F e0 (uniform)

    auto Mstr = [&](){   // strided: partner flips c bit0 = lane bit5
        const bool upm = (lane & 32) != 0;
        const float sgm = upm ? -1.0f : 1.0f;
        #pragma unroll
        for (int j = 0; j < 4; ++j){
            float2 o = p32_2(z[j], upm);
            z[j] = make_float2(fmaf(sgm, z[j].x, o.x), fmaf(sgm, z[j].y, o.y));
        }
    };
    auto Mcon = [&](){   // consecutive: pairs flip j bit0
        float2 a0 = z[0], b0 = z[1], a1 = z[2], b1 = z[3];
        z[0] = cadd(a0, b0); z[1] = csub(a0, b0);
        z[2] = cadd(a1, b1); z[3] = csub(a1, b1);
    };
    auto Dstr = [&](int l){  // t = 64*(wid + 4j) + c
        const float* p = W + l * TLEN + c + 64 * wid;
        #pragma unroll
        for (int j = 0; j < 4; ++j){
            float sv, cv; __sincosf(p[j << 8], &sv, &cv);
            z[j] = cmul(z[j], make_float2(cv, sv));
        }
    };
    auto Dcon = [&](int l){  // t = 16*lane + 4*wid + j
        float4 wv = *(const float4*)(W + l * TLEN + 16 * lane + 4 * wid);
        float ws[4] = {wv.x, wv.y, wv.z, wv.w};
        #pragma unroll
        for (int j = 0; j < 4; ++j){
            float sv, cv; __sincosf(ws[j], &sv, &cv);
            z[j] = cmul(z[j], make_float2(cv, sv));
        }
    };
    auto midtw = [&](){
        #pragma unroll
        for (int j = 0; j < 4; ++j) z[j] = cmul(z[j], wmv[j]);
    };
    // FFT-16 over r, input (w,j) holds r = 4w+j -> output (w,j) holds X[w+4j]
    auto fft16A = [&](){
        #pragma unroll
        for (int j = 0; j < 4; ++j) xbuf[(wid * 4 + j) * 64 + lane] = z[j];
        __syncthreads();
        float2 u[4];
        #pragma unroll
        for (int j = 0; j < 4; ++j){
            float2 x0 = xbuf[(0 * 4 + j) * 64 + lane];
            float2 x1 = xbuf[(1 * 4 + j) * 64 + lane];
            float2 x2 = xbuf[(2 * 4 + j) * 64 + lane];
            float2 x3 = xbuf[(3 * 4 + j) * 64 + lane];
            u[j] = combine4(x0, x1, x2, x3, wid);
        }
        __syncthreads();
        tw16(u, wid);                       // W16^{j*wid}
        dft4(u[0], u[1], u[2], u[3], z[0], z[1], z[2], z[3]);  // over j -> j'
    };
    // FFT-16 over r, input (w,j) holds r = w+4j -> output (w,j) holds X[4w+j]
    auto fft16B = [&](){
        float2 u[4];
        dft4(z[0], z[1], z[2], z[3], u[0], u[1], u[2], u[3]);  // over j -> j'
        tw16(u, wid);                       // W16^{wid*j'}
        #pragma unroll
        for (int j = 0; j < 4; ++j) xbuf[(wid * 4 + j) * 64 + lane] = u[j];
        __syncthreads();
        #pragma unroll
        for (int j = 0; j < 4; ++j){
            float2 x0 = xbuf[(0 * 4 + j) * 64 + lane];
            float2 x1 = xbuf[(1 * 4 + j) * 64 + lane];
            float2 x2 = xbuf[(2 * 4 + j) * 64 + lane];
            float2 x3 = xbuf[(3 * 4 + j) * 64 + lane];
            z[j] = combine4(x0, x1, x2, x3, wid);
        }
        __syncthreads();
    };
    // full DFTs: A = consecutive -> strided-bitrev; B = strided-bitrev -> consecutive
    auto dftA = [&](){ xfft_dif4(z, Wt, lane); midtw(); fft16A(); };
    auto dftB = [&](){ fft16B(); midtw(); xfft_dit4(z, Wt, lane); };

    // chain: v = e0; for l=5..0: v = D_l M F v.   F#1 folded into init.
    Mstr(); Dstr(5);
    dftB(); Mcon(); Dcon(4);
    dftA(); Mstr(); Dstr(3);
    dftB(); Mcon(); Dcon(2);
    dftA(); Mstr(); Dstr(1);
    dftB(); Mcon(); Dcon(0);

    // store consecutive: a[16*lane + 4*wid + j]
    float4* pout = (float4*)(a_out + 16 * lane + 4 * wid);
    pout[0] = make_float4(z[0].x, z[0].y, z[1].x, z[1].y);
    pout[1] = make_float4(z[2].x, z[2].y, z[3].x, z[3].y);
}

// ============================================================================
// dot: out[row] = (sin(angle(a . z_row)) + 1)/2,  z_t = (sqrt(1-x^2), x)
// ============================================================================
__global__ __launch_bounds__(256)
void dot_kernel(const float* __restrict__ X,
                const float2* __restrict__ a,
                float* __restrict__ out)
{
    const int lane = threadIdx.x & 63;
    const int row  = blockIdx.x * 4 + (threadIdx.x >> 6);

    const float4* px = (const float4*)(X + (size_t)row * TLEN + lane * 16);
    const float4* pa = (const float4*)(a + lane * 16);

    float re = 0.0f, im = 0.0f;
    #pragma unroll
    for (int i = 0; i < 4; ++i){
        float4 xv = px[i];
        float4 qa = pa[2*i];
        float4 qb = pa[2*i + 1];
        float xs[4] = {xv.x, xv.y, xv.z, xv.w};
        float ar[4] = {qa.x, qa.z, qb.x, qb.z};
        float ai[4] = {qa.y, qa.w, qb.y, qb.w};
        #pragma unroll
        for (int j = 0; j < 4; ++j){
            float x  = fminf(fmaxf(xs[j], -0.999f), 0.999f);
            float cc = sqrtf(fmaf(-x, x, 1.0f));
            re = fmaf(ar[j], cc, re);  re = fmaf(-ai[j], x,  re);
            im = fmaf(ar[j], x,  im);  im = fmaf( ai[j], cc, im);
        }
    }

    float2 s = make_float2(re, im);
    s = cadd(s, dpp2<DPP_XOR1>(s));
    s = cadd(s, dpp2<DPP_XOR2>(s));
    s = cadd(s, swz2<SWZ_XOR4>(s));
    s = cadd(s, dpp2<DPP_XOR8>(s));
    s = cadd(s, swz2<SWZ_XOR16>(s));
    s = cadd(s, p32_2(s, (lane & 32) != 0));

    if (lane == 0){
        out[row] = fmaf(s.y * rsqrtf(fmaf(s.x, s.x, s.y * s.y)), 0.5f, 0.5f);
    }
}

extern "C" void kernel_launch(void* const* d_in, const int* in_sizes, int n_in,
                              void* d_out, int out_size, void* d_ws, size_t ws_size,
                              hipStream_t stream) {
    const float* X = (const float*)d_in[0];   // [4096, 1024]
    const float* W = (const float*)d_in[1];   // [6*1024]
    float* out = (float*)d_out;               // [4096]
    (void)in_sizes; (void)n_in; (void)out_size; (void)ws_size;

    float2* aW = (float2*)d_ws;               // 8 KiB of workspace

    prep_kernel<<<1, 256, 0, stream>>>(W, aW);
    dot_kernel<<<4096 / 4, 256, 0, stream>>>(X, aW, out);
}

// Round 9
// 19.344 us; speedup vs baseline: 1.6512x; 1.0627x over previous
//
#include <hip/hip_runtime.h>
#include <math.h>

#define TLEN 1024

typedef int i32x2 __attribute__((ext_vector_type(2)));

__device__ __forceinline__ float2 cadd(float2 a, float2 b){ return make_float2(a.x+b.x, a.y+b.y); }
__device__ __forceinline__ float2 csub(float2 a, float2 b){ return make_float2(a.x-b.x, a.y-b.y); }
__device__ __forceinline__ float2 cmul(float2 a, float2 b){
    return make_float2(fmaf(a.x, b.x, -(a.y*b.y)), fmaf(a.x, b.y, a.y*b.x));
}
__device__ __forceinline__ float2 cmulnegi(float2 a){ return make_float2(a.y, -a.x); }  // a * (-i)
__device__ __forceinline__ float2 cmulposi(float2 a){ return make_float2(-a.y, a.x); }  // a * (+i)
__device__ __forceinline__ int bitrev6(int l){
    return ((l & 1) << 5) | ((l & 2) << 3) | ((l & 4) << 1)
         | ((l & 8) >> 1) | ((l & 16) >> 3) | ((l & 32) >> 5);
}

// ---- cross-lane partner primitives (verified R4) ----
#define DPP_XOR1  0xB1   // quad_perm [1,0,3,2]
#define DPP_XOR2  0x4E   // quad_perm [2,3,0,1]
#define DPP_XOR8  0x128  // row_ror:8
#define SWZ_XOR4  0x101F // bitmode xor=4
#define SWZ_XOR16 0x401F // bitmode xor=16

template<int CTRL>
__device__ __forceinline__ float2 dpp2(float2 v){
    return make_float2(
        __int_as_float(__builtin_amdgcn_mov_dpp(__float_as_int(v.x), CTRL, 0xF, 0xF, false)),
        __int_as_float(__builtin_amdgcn_mov_dpp(__float_as_int(v.y), CTRL, 0xF, 0xF, false)));
}
template<int PAT>
__device__ __forceinline__ float2 swz2(float2 v){
    return make_float2(
        __int_as_float(__builtin_amdgcn_ds_swizzle(__float_as_int(v.x), PAT)),
        __int_as_float(__builtin_amdgcn_ds_swizzle(__float_as_int(v.y), PAT)));
}
__device__ __forceinline__ float p32f(float v, bool up){
#if __has_builtin(__builtin_amdgcn_permlane32_swap)
    i32x2 r = __builtin_amdgcn_permlane32_swap(__float_as_int(v), __float_as_int(v), false, false);
    return __int_as_float(up ? r[0] : r[1]);
#else
    int a = __float_as_int(v), b = __float_as_int(v);
    asm("v_permlane32_swap_b32 %0, %1" : "+v"(a), "+v"(b));
    return __int_as_float(up ? a : b);
#endif
}
__device__ __forceinline__ float2 p32_2(float2 v, bool up){
    return make_float2(p32f(v.x, up), p32f(v.y, up));
}

// DFT-4: y_k = sum_a x_a W4^{ak}
__device__ __forceinline__ void dft4(float2 x0, float2 x1, float2 x2, float2 x3,
                                     float2& y0, float2& y1, float2& y2, float2& y3){
    float2 t0 = cadd(x0, x2);
    float2 t1 = csub(x0, x2);
    float2 t2 = cadd(x1, x3);
    float2 t3 = csub(x1, x3);
    float2 n3 = cmulnegi(t3);
    y0 = cadd(t0, t2);
    y2 = csub(t0, t2);
    y1 = cadd(t1, n3);
    y3 = csub(t1, n3);
}

// selected output k of DFT-4 (k wave-uniform)
__device__ __forceinline__ float2 combine4(float2 x0, float2 x1, float2 x2, float2 x3, int k){
    float2 e = cadd(x0, x2), f = csub(x0, x2);
    float2 g = cadd(x1, x3), h = csub(x1, x3);
    if (k == 0) return cadd(e, g);
    if (k == 1) return cadd(f, cmulnegi(h));
    if (k == 2) return csub(e, g);
    return cadd(f, cmulposi(h));
}

// u[j] *= W16^{j*e}, e wave-uniform in [0,4)
__device__ __forceinline__ void tw16(float2 u[4], int e){
    const float C1 = 0.92387953251128675613f, S1 = 0.38268343236508977173f;
    const float H  = 0.70710678118654752440f;
    if (e == 1){
        u[1] = cmul(u[1], make_float2( C1, -S1));
        u[2] = cmul(u[2], make_float2(  H,  -H));
        u[3] = cmul(u[3], make_float2( S1, -C1));
    } else if (e == 2){
        u[1] = cmul(u[1], make_float2(  H,  -H));
        u[2] = cmulnegi(u[2]);
        u[3] = cmul(u[3], make_float2( -H,  -H));
    } else if (e == 3){
        u[1] = cmul(u[1], make_float2( S1, -C1));
        u[2] = cmul(u[2], make_float2( -H,  -H));
        u[3] = cmul(u[3], make_float2(-C1,  S1));
    }
}

// ---- cross-lane FFT-64 over lanes, 4 regs (verified R4/R8) ----
template<bool TW, typename F>
__device__ __forceinline__ void dif_stage4(float2 z[4], F partner, float sg, float2 w){
    #pragma unroll
    for (int r = 0; r < 4; ++r){
        float2 o = partner(z[r]);
        float2 pre = make_float2(fmaf(sg, z[r].x, o.x), fmaf(sg, z[r].y, o.y));
        z[r] = TW ? cmul(pre, w) : pre;
    }
}
template<bool TW, typename F>
__device__ __forceinline__ void dit_stage4(float2 z[4], F partner, float sg, float2 w){
    #pragma unroll
    for (int r = 0; r < 4; ++r){
        float2 zz = TW ? cmul(z[r], w) : z[r];
        float2 o = partner(zz);
        z[r] = make_float2(fmaf(sg, zz.x, o.x), fmaf(sg, zz.y, o.y));
    }
}
__device__ __forceinline__ void xfft_dif4(float2 z[4], const float2 Wt[5], int lane){
    const float2 ONE = make_float2(1.0f, 0.0f);
    {   const bool up = (lane & 32) != 0; const float sg = up ? -1.0f : 1.0f;
        dif_stage4<true>(z, [&](float2 v){ return p32_2(v, up); }, sg, up ? Wt[4] : ONE); }
    {   const bool up = (lane & 16) != 0; const float sg = up ? -1.0f : 1.0f;
        dif_stage4<true>(z, [](float2 v){ return swz2<SWZ_XOR16>(v); }, sg, up ? Wt[3] : ONE); }
    {   const bool up = (lane & 8) != 0;  const float sg = up ? -1.0f : 1.0f;
        dif_stage4<true>(z, [](float2 v){ return dpp2<DPP_XOR8>(v); }, sg, up ? Wt[2] : ONE); }
    {   const bool up = (lane & 4) != 0;  const float sg = up ? -1.0f : 1.0f;
        dif_stage4<true>(z, [](float2 v){ return swz2<SWZ_XOR4>(v); }, sg, up ? Wt[1] : ONE); }
    {   const bool up = (lane & 2) != 0;  const float sg = up ? -1.0f : 1.0f;
        dif_stage4<true>(z, [](float2 v){ return dpp2<DPP_XOR2>(v); }, sg, up ? Wt[0] : ONE); }
    {   const float sg = (lane & 1) ? -1.0f : 1.0f;
        dif_stage4<false>(z, [](float2 v){ return dpp2<DPP_XOR1>(v); }, sg, ONE); }
}
__device__ __forceinline__ void xfft_dit4(float2 z[4], const float2 Wt[5], int lane){
    const float2 ONE = make_float2(1.0f, 0.0f);
    {   const float sg = (lane & 1) ? -1.0f : 1.0f;
        dit_stage4<false>(z, [](float2 v){ return dpp2<DPP_XOR1>(v); }, sg, ONE); }
    {   const bool up = (lane & 2) != 0;  const float sg = up ? -1.0f : 1.0f;
        dit_stage4<true>(z, [](float2 v){ return dpp2<DPP_XOR2>(v); }, sg, up ? Wt[0] : ONE); }
    {   const bool up = (lane & 4) != 0;  const float sg = up ? -1.0f : 1.0f;
        dit_stage4<true>(z, [](float2 v){ return swz2<SWZ_XOR4>(v); }, sg, up ? Wt[1] : ONE); }
    {   const bool up = (lane & 8) != 0;  const float sg = up ? -1.0f : 1.0f;
        dit_stage4<true>(z, [](float2 v){ return dpp2<DPP_XOR8>(v); }, sg, up ? Wt[2] : ONE); }
    {   const bool up = (lane & 16) != 0; const float sg = up ? -1.0f : 1.0f;
        dit_stage4<true>(z, [](float2 v){ return swz2<SWZ_XOR16>(v); }, sg, up ? Wt[3] : ONE); }
    {   const bool up = (lane & 32) != 0; const float sg = up ? -1.0f : 1.0f;
        dit_stage4<true>(z, [&](float2 v){ return p32_2(v, up); }, sg, up ? Wt[4] : ONE); }
}

// ============================================================================
// fused: every block redundantly computes a = (D_0 M F)...(D_5 M F) e_0 with
// waves 0-3 (R8 chain verbatim, 10 internal barriers), stores a transposed to
// LDS (barrier #11), then all 8 waves dot their own row against prefetched X.
// Waves 4-7 spin 11 matching barriers during prep.
// ============================================================================
__global__ __launch_bounds__(512, 4)
void fused_kernel(const float* __restrict__ X,
                  const float* __restrict__ W,
                  float* __restrict__ out)
{
    __shared__ float2 xbuf[16 * 64];   // 8 KiB: chain exchange, then a[r][lane]

    const int lane = threadIdx.x & 63;
    const int wid  = threadIdx.x >> 6;   // 0..7
    const int row  = blockIdx.x * 8 + wid;

    // ---- prefetch own row of X (hides HBM under prep chain) ----
    float4 xr[4];
    {
        const float4* px = (const float4*)(X + (size_t)row * TLEN + lane * 16);
        #pragma unroll
        for (int i = 0; i < 4; ++i) xr[i] = px[i];
    }

    if (wid < 4){
        // ================= prep chain (waves 0-3), verbatim R8 =================
        const int c = bitrev6(lane);
        float2 Wt[5];
        #pragma unroll
        for (int k = 0; k < 5; ++k){
            const int h = 2 << k;
            float sv, cv;
            sincosf(-3.14159265358979323846f * (float)(lane & (h - 1)) / (float)h, &sv, &cv);
            Wt[k] = make_float2(cv, sv);
        }
        float2 wmv[4];
        {
            const float theta = -6.28318530717958647692f * (float)c / 1024.0f;
            float sv, cv;
            __sincosf(theta * (float)(4 * wid), &sv, &cv); float2 base = make_float2(cv, sv);
            __sincosf(theta, &sv, &cv);                    float2 step = make_float2(cv, sv);
            wmv[0] = base;
            wmv[1] = cmul(wmv[0], step);
            wmv[2] = cmul(wmv[1], step);
            wmv[3] = cmul(wmv[2], step);
        }

        float2 z[4];
        #pragma unroll
        for (int j = 0; j < 4; ++j) z[j] = make_float2(1.0f, 0.0f);  // F e0 (uniform)

        auto Mstr = [&](){
            const bool upm = (lane & 32) != 0;
            const float sgm = upm ? -1.0f : 1.0f;
            #pragma unroll
            for (int j = 0; j < 4; ++j){
                float2 o = p32_2(z[j], upm);
                z[j] = make_float2(fmaf(sgm, z[j].x, o.x), fmaf(sgm, z[j].y, o.y));
            }
        };
        auto Mcon = [&](){
            float2 a0 = z[0], b0 = z[1], a1 = z[2], b1 = z[3];
            z[0] = cadd(a0, b0); z[1] = csub(a0, b0);
            z[2] = cadd(a1, b1); z[3] = csub(a1, b1);
        };
        auto Dstr = [&](int l){  // t = 64*(wid + 4j) + c
            const float* p = W + l * TLEN + c + 64 * wid;
            #pragma unroll
            for (int j = 0; j < 4; ++j){
                float sv, cv; __sincosf(p[j << 8], &sv, &cv);
                z[j] = cmul(z[j], make_float2(cv, sv));
            }
        };
        auto Dcon = [&](int l){  // t = 16*lane + 4*wid + j
            float4 wv = *(const float4*)(W + l * TLEN + 16 * lane + 4 * wid);
            float ws[4] = {wv.x, wv.y, wv.z, wv.w};
            #pragma unroll
            for (int j = 0; j < 4; ++j){
                float sv, cv; __sincosf(ws[j], &sv, &cv);
                z[j] = cmul(z[j], make_float2(cv, sv));
            }
        };
        auto midtw = [&](){
            #pragma unroll
            for (int j = 0; j < 4; ++j) z[j] = cmul(z[j], wmv[j]);
        };
        auto fft16A = [&](){   // 2 barriers
            #pragma unroll
            for (int j = 0; j < 4; ++j) xbuf[(wid * 4 + j) * 64 + lane] = z[j];
            __syncthreads();
            float2 u[4];
            #pragma unroll
            for (int j = 0; j < 4; ++j){
                float2 x0 = xbuf[(0 * 4 + j) * 64 + lane];
                float2 x1 = xbuf[(1 * 4 + j) * 64 + lane];
                float2 x2 = xbuf[(2 * 4 + j) * 64 + lane];
                float2 x3 = xbuf[(3 * 4 + j) * 64 + lane];
                u[j] = combine4(x0, x1, x2, x3, wid);
            }
            __syncthreads();
            tw16(u, wid);
            dft4(u[0], u[1], u[2], u[3], z[0], z[1], z[2], z[3]);
        };
        auto fft16B = [&](){   // 2 barriers
            float2 u[4];
            dft4(z[0], z[1], z[2], z[3], u[0], u[1], u[2], u[3]);
            tw16(u, wid);
            #pragma unroll
            for (int j = 0; j < 4; ++j) xbuf[(wid * 4 + j) * 64 + lane] = u[j];
            __syncthreads();
            #pragma unroll
            for (int j = 0; j < 4; ++j){
                float2 x0 = xbuf[(0 * 4 + j) * 64 + lane];
                float2 x1 = xbuf[(1 * 4 + j) * 64 + lane];
                float2 x2 = xbuf[(2 * 4 + j) * 64 + lane];
                float2 x3 = xbuf[(3 * 4 + j) * 64 + lane];
                z[j] = combine4(x0, x1, x2, x3, wid);
            }
            __syncthreads();
        };
        auto dftA = [&](){ xfft_dif4(z, Wt, lane); midtw(); fft16A(); };
        auto dftB = [&](){ fft16B(); midtw(); xfft_dit4(z, Wt, lane); };

        // chain: v = e0; for l=5..0: v = D_l M F v.  (F#1 folded into init)
        Mstr(); Dstr(5);
        dftB(); Mcon(); Dcon(4);    // 2 barriers
        dftA(); Mstr(); Dstr(3);    // 2
        dftB(); Mcon(); Dcon(2);    // 2
        dftA(); Mstr(); Dstr(1);    // 2
        dftB(); Mcon(); Dcon(0);    // 2  -> 10 total
        // store a transposed: a[16*l + 4*wid + j] -> xbuf[(4*wid+j)*64 + l]
        #pragma unroll
        for (int j = 0; j < 4; ++j) xbuf[(4 * wid + j) * 64 + lane] = z[j];
        __syncthreads();            // barrier #11
    } else {
        // waves 4-7: match the chain's 11 barriers
        for (int i = 0; i < 11; ++i) __syncthreads();
    }

    // ================= dot phase: every wave its own row =================
    float re = 0.0f, im = 0.0f;
    #pragma unroll
    for (int i = 0; i < 4; ++i){
        float4 xv = xr[i];
        float xs[4] = {xv.x, xv.y, xv.z, xv.w};
        #pragma unroll
        for (int j = 0; j < 4; ++j){
            float2 av = xbuf[(4 * i + j) * 64 + lane];   // a[16*lane + 4i + j]
            float x  = fminf(fmaxf(xs[j], -0.999f), 0.999f);
            float cc = sqrtf(fmaf(-x, x, 1.0f));
            re = fmaf(av.x, cc, re);  re = fmaf(-av.y, x,  re);
            im = fmaf(av.x, x,  im);  im = fmaf( av.y, cc, im);
        }
    }

    float2 s = make_float2(re, im);
    s = cadd(s, dpp2<DPP_XOR1>(s));
    s = cadd(s, dpp2<DPP_XOR2>(s));
    s = cadd(s, swz2<SWZ_XOR4>(s));
    s = cadd(s, dpp2<DPP_XOR8>(s));
    s = cadd(s, swz2<SWZ_XOR16>(s));
    s = cadd(s, p32_2(s, (lane & 32) != 0));

    if (lane == 0){
        out[row] = fmaf(s.y * rsqrtf(fmaf(s.x, s.x, s.y * s.y)), 0.5f, 0.5f);
    }
}

extern "C" void kernel_launch(void* const* d_in, const int* in_sizes, int n_in,
                              void* d_out, int out_size, void* d_ws, size_t ws_size,
                              hipStream_t stream) {
    const float* X = (const float*)d_in[0];   // [4096, 1024]
    const float* W = (const float*)d_in[1];   // [6*1024]
    float* out = (float*)d_out;               // [4096]
    (void)in_sizes; (void)n_in; (void)out_size; (void)d_ws; (void)ws_size;

    fused_kernel<<<4096 / 8, 512, 0, stream>>>(X, W, out);
}

// Round 10
// 18.014 us; speedup vs baseline: 1.7732x; 1.0738x over previous
//
#include <hip/hip_runtime.h>
#include <math.h>

#define TLEN 1024

typedef int i32x2 __attribute__((ext_vector_type(2)));

__device__ __forceinline__ float2 cadd(float2 a, float2 b){ return make_float2(a.x+b.x, a.y+b.y); }
__device__ __forceinline__ float2 csub(float2 a, float2 b){ return make_float2(a.x-b.x, a.y-b.y); }
__device__ __forceinline__ float2 cmul(float2 a, float2 b){
    return make_float2(fmaf(a.x, b.x, -(a.y*b.y)), fmaf(a.x, b.y, a.y*b.x));
}
__device__ __forceinline__ float2 cmulnegi(float2 a){ return make_float2(a.y, -a.x); }  // a * (-i)
__device__ __forceinline__ float2 cmulposi(float2 a){ return make_float2(-a.y, a.x); }  // a * (+i)
__device__ __forceinline__ int bitrev6(int l){
    return ((l & 1) << 5) | ((l & 2) << 3) | ((l & 4) << 1)
         | ((l & 8) >> 1) | ((l & 16) >> 3) | ((l & 32) >> 5);
}

// ---- cross-lane partner primitives (verified R4) ----
#define DPP_XOR1  0xB1   // quad_perm [1,0,3,2]
#define DPP_XOR2  0x4E   // quad_perm [2,3,0,1]
#define DPP_XOR8  0x128  // row_ror:8
#define SWZ_XOR4  0x101F // bitmode xor=4
#define SWZ_XOR16 0x401F // bitmode xor=16

template<int CTRL>
__device__ __forceinline__ float2 dpp2(float2 v){
    return make_float2(
        __int_as_float(__builtin_amdgcn_mov_dpp(__float_as_int(v.x), CTRL, 0xF, 0xF, false)),
        __int_as_float(__builtin_amdgcn_mov_dpp(__float_as_int(v.y), CTRL, 0xF, 0xF, false)));
}
template<int PAT>
__device__ __forceinline__ float2 swz2(float2 v){
    return make_float2(
        __int_as_float(__builtin_amdgcn_ds_swizzle(__float_as_int(v.x), PAT)),
        __int_as_float(__builtin_amdgcn_ds_swizzle(__float_as_int(v.y), PAT)));
}
__device__ __forceinline__ float p32f(float v, bool up){
#if __has_builtin(__builtin_amdgcn_permlane32_swap)
    i32x2 r = __builtin_amdgcn_permlane32_swap(__float_as_int(v), __float_as_int(v), false, false);
    return __int_as_float(up ? r[0] : r[1]);
#else
    int a = __float_as_int(v), b = __float_as_int(v);
    asm("v_permlane32_swap_b32 %0, %1" : "+v"(a), "+v"(b));
    return __int_as_float(up ? a : b);
#endif
}
__device__ __forceinline__ float2 p32_2(float2 v, bool up){
    return make_float2(p32f(v.x, up), p32f(v.y, up));
}

// DFT-4: y_k = sum_a x_a W4^{ak}
__device__ __forceinline__ void dft4(float2 x0, float2 x1, float2 x2, float2 x3,
                                     float2& y0, float2& y1, float2& y2, float2& y3){
    float2 t0 = cadd(x0, x2);
    float2 t1 = csub(x0, x2);
    float2 t2 = cadd(x1, x3);
    float2 t3 = csub(x1, x3);
    float2 n3 = cmulnegi(t3);
    y0 = cadd(t0, t2);
    y2 = csub(t0, t2);
    y1 = cadd(t1, n3);
    y3 = csub(t1, n3);
}

// selected output k of DFT-4 (k wave-uniform)
__device__ __forceinline__ float2 combine4(float2 x0, float2 x1, float2 x2, float2 x3, int k){
    float2 e = cadd(x0, x2), f = csub(x0, x2);
    float2 g = cadd(x1, x3), h = csub(x1, x3);
    if (k == 0) return cadd(e, g);
    if (k == 1) return cadd(f, cmulnegi(h));
    if (k == 2) return csub(e, g);
    return cadd(f, cmulposi(h));
}

// u[j] *= W16^{j*e}, e wave-uniform in [0,4)
__device__ __forceinline__ void tw16(float2 u[4], int e){
    const float C1 = 0.92387953251128675613f, S1 = 0.38268343236508977173f;
    const float H  = 0.70710678118654752440f;
    if (e == 1){
        u[1] = cmul(u[1], make_float2( C1, -S1));
        u[2] = cmul(u[2], make_float2(  H,  -H));
        u[3] = cmul(u[3], make_float2( S1, -C1));
    } else if (e == 2){
        u[1] = cmul(u[1], make_float2(  H,  -H));
        u[2] = cmulnegi(u[2]);
        u[3] = cmul(u[3], make_float2( -H,  -H));
    } else if (e == 3){
        u[1] = cmul(u[1], make_float2( S1, -C1));
        u[2] = cmul(u[2], make_float2( -H,  -H));
        u[3] = cmul(u[3], make_float2(-C1,  S1));
    }
}

// ---- cross-lane FFT-64 over lanes, 4 regs (verified R4/R8) ----
template<bool TW, typename F>
__device__ __forceinline__ void dif_stage4(float2 z[4], F partner, float sg, float2 w){
    #pragma unroll
    for (int r = 0; r < 4; ++r){
        float2 o = partner(z[r]);
        float2 pre = make_float2(fmaf(sg, z[r].x, o.x), fmaf(sg, z[r].y, o.y));
        z[r] = TW ? cmul(pre, w) : pre;
    }
}
template<bool TW, typename F>
__device__ __forceinline__ void dit_stage4(float2 z[4], F partner, float sg, float2 w){
    #pragma unroll
    for (int r = 0; r < 4; ++r){
        float2 zz = TW ? cmul(z[r], w) : z[r];
        float2 o = partner(zz);
        z[r] = make_float2(fmaf(sg, zz.x, o.x), fmaf(sg, zz.y, o.y));
    }
}
__device__ __forceinline__ void xfft_dif4(float2 z[4], const float2 Wt[5], int lane){
    const float2 ONE = make_float2(1.0f, 0.0f);
    {   const bool up = (lane & 32) != 0; const float sg = up ? -1.0f : 1.0f;
        dif_stage4<true>(z, [&](float2 v){ return p32_2(v, up); }, sg, up ? Wt[4] : ONE); }
    {   const bool up = (lane & 16) != 0; const float sg = up ? -1.0f : 1.0f;
        dif_stage4<true>(z, [](float2 v){ return swz2<SWZ_XOR16>(v); }, sg, up ? Wt[3] : ONE); }
    {   const bool up = (lane & 8) != 0;  const float sg = up ? -1.0f : 1.0f;
        dif_stage4<true>(z, [](float2 v){ return dpp2<DPP_XOR8>(v); }, sg, up ? Wt[2] : ONE); }
    {   const bool up = (lane & 4) != 0;  const float sg = up ? -1.0f : 1.0f;
        dif_stage4<true>(z, [](float2 v){ return swz2<SWZ_XOR4>(v); }, sg, up ? Wt[1] : ONE); }
    {   const bool up = (lane & 2) != 0;  const float sg = up ? -1.0f : 1.0f;
        dif_stage4<true>(z, [](float2 v){ return dpp2<DPP_XOR2>(v); }, sg, up ? Wt[0] : ONE); }
    {   const float sg = (lane & 1) ? -1.0f : 1.0f;
        dif_stage4<false>(z, [](float2 v){ return dpp2<DPP_XOR1>(v); }, sg, ONE); }
}
__device__ __forceinline__ void xfft_dit4(float2 z[4], const float2 Wt[5], int lane){
    const float2 ONE = make_float2(1.0f, 0.0f);
    {   const float sg = (lane & 1) ? -1.0f : 1.0f;
        dit_stage4<false>(z, [](float2 v){ return dpp2<DPP_XOR1>(v); }, sg, ONE); }
    {   const bool up = (lane & 2) != 0;  const float sg = up ? -1.0f : 1.0f;
        dit_stage4<true>(z, [](float2 v){ return dpp2<DPP_XOR2>(v); }, sg, up ? Wt[0] : ONE); }
    {   const bool up = (lane & 4) != 0;  const float sg = up ? -1.0f : 1.0f;
        dit_stage4<true>(z, [](float2 v){ return swz2<SWZ_XOR4>(v); }, sg, up ? Wt[1] : ONE); }
    {   const bool up = (lane & 8) != 0;  const float sg = up ? -1.0f : 1.0f;
        dit_stage4<true>(z, [](float2 v){ return dpp2<DPP_XOR8>(v); }, sg, up ? Wt[2] : ONE); }
    {   const bool up = (lane & 16) != 0; const float sg = up ? -1.0f : 1.0f;
        dit_stage4<true>(z, [](float2 v){ return swz2<SWZ_XOR16>(v); }, sg, up ? Wt[3] : ONE); }
    {   const bool up = (lane & 32) != 0; const float sg = up ? -1.0f : 1.0f;
        dit_stage4<true>(z, [&](float2 v){ return p32_2(v, up); }, sg, up ? Wt[4] : ONE); }
}

// ============================================================================
// fused v2: looped chain (small code), all __sincosf, double-buffered
// exchange -> 6 barriers total. Waves 0-3 compute a; waves 4-7 spin 6
// barriers; all 8 waves dot their prefetched row.
// ============================================================================
__global__ __launch_bounds__(512, 4)
void fused_kernel(const float* __restrict__ X,
                  const float* __restrict__ W,
                  float* __restrict__ out)
{
    __shared__ float2 xb0[16 * 64];   // exchange buffer A (8 KiB)
    __shared__ float2 xb1[16 * 64];   // exchange buffer B / final a (8 KiB)

    const int lane = threadIdx.x & 63;
    const int wid  = threadIdx.x >> 6;   // 0..7
    const int row  = blockIdx.x * 8 + wid;

    // ---- prefetch own row of X (no wait until dot phase) ----
    float4 xr[4];
    {
        const float4* px = (const float4*)(X + (size_t)row * TLEN + lane * 16);
        #pragma unroll
        for (int i = 0; i < 4; ++i) xr[i] = px[i];
    }

    if (wid < 4){
        // ================= prep chain (waves 0-3) =================
        const int c = bitrev6(lane);
        float2 Wt[5];
        #pragma unroll
        for (int k = 0; k < 5; ++k){
            const int h = 2 << k;
            float sv, cv;
            __sincosf(-3.14159265358979323846f * (float)(lane & (h - 1)) / (float)h, &sv, &cv);
            Wt[k] = make_float2(cv, sv);
        }
        float2 wmv[4];
        {
            const float theta = -6.28318530717958647692f * (float)c / 1024.0f;
            float sv, cv;
            __sincosf(theta * (float)(4 * wid), &sv, &cv); float2 base = make_float2(cv, sv);
            __sincosf(theta, &sv, &cv);                    float2 step = make_float2(cv, sv);
            wmv[0] = base;
            wmv[1] = cmul(wmv[0], step);
            wmv[2] = cmul(wmv[1], step);
            wmv[3] = cmul(wmv[2], step);
        }

        float2 z[4];
        #pragma unroll
        for (int j = 0; j < 4; ++j) z[j] = make_float2(1.0f, 0.0f);  // F e0 (uniform)

        auto Mstr = [&](){
            const bool upm = (lane & 32) != 0;
            const float sgm = upm ? -1.0f : 1.0f;
            #pragma unroll
            for (int j = 0; j < 4; ++j){
                float2 o = p32_2(z[j], upm);
                z[j] = make_float2(fmaf(sgm, z[j].x, o.x), fmaf(sgm, z[j].y, o.y));
            }
        };
        auto Mcon = [&](){
            float2 a0 = z[0], b0 = z[1], a1 = z[2], b1 = z[3];
            z[0] = cadd(a0, b0); z[1] = csub(a0, b0);
            z[2] = cadd(a1, b1); z[3] = csub(a1, b1);
        };
        auto Dstr = [&](int l){  // t = 64*(wid + 4j) + c
            const float* p = W + l * TLEN + c + 64 * wid;
            #pragma unroll
            for (int j = 0; j < 4; ++j){
                float sv, cv; __sincosf(p[j << 8], &sv, &cv);
                z[j] = cmul(z[j], make_float2(cv, sv));
            }
        };
        auto Dcon = [&](int l){  // t = 16*lane + 4*wid + j
            float4 wv = *(const float4*)(W + l * TLEN + 16 * lane + 4 * wid);
            float ws[4] = {wv.x, wv.y, wv.z, wv.w};
            #pragma unroll
            for (int j = 0; j < 4; ++j){
                float sv, cv; __sincosf(ws[j], &sv, &cv);
                z[j] = cmul(z[j], make_float2(cv, sv));
            }
        };
        auto midtw = [&](){
            #pragma unroll
            for (int j = 0; j < 4; ++j) z[j] = cmul(z[j], wmv[j]);
        };
        // FFT-16 over r, input (w,j) holds r = 4w+j -> output (w,j) holds X[w+4j]
        // one barrier (write xb1, bar, read xb1)
        auto fft16A = [&](){
            #pragma unroll
            for (int j = 0; j < 4; ++j) xb1[(wid * 4 + j) * 64 + lane] = z[j];
            __syncthreads();
            float2 u[4];
            #pragma unroll
            for (int j = 0; j < 4; ++j){
                float2 x0 = xb1[(0 * 4 + j) * 64 + lane];
                float2 x1 = xb1[(1 * 4 + j) * 64 + lane];
                float2 x2 = xb1[(2 * 4 + j) * 64 + lane];
                float2 x3 = xb1[(3 * 4 + j) * 64 + lane];
                u[j] = combine4(x0, x1, x2, x3, wid);
            }
            tw16(u, wid);
            dft4(u[0], u[1], u[2], u[3], z[0], z[1], z[2], z[3]);
        };
        // FFT-16 over r, input (w,j) holds r = w+4j -> output (w,j) holds X[4w+j]
        // one barrier (write xb0, bar, read xb0)
        auto fft16B = [&](){
            float2 u[4];
            dft4(z[0], z[1], z[2], z[3], u[0], u[1], u[2], u[3]);
            tw16(u, wid);
            #pragma unroll
            for (int j = 0; j < 4; ++j) xb0[(wid * 4 + j) * 64 + lane] = u[j];
            __syncthreads();
            #pragma unroll
            for (int j = 0; j < 4; ++j){
                float2 x0 = xb0[(0 * 4 + j) * 64 + lane];
                float2 x1 = xb0[(1 * 4 + j) * 64 + lane];
                float2 x2 = xb0[(2 * 4 + j) * 64 + lane];
                float2 x3 = xb0[(3 * 4 + j) * 64 + lane];
                z[j] = combine4(x0, x1, x2, x3, wid);
            }
        };
        auto dftA = [&](){ xfft_dif4(z, Wt, lane); midtw(); fft16A(); };
        auto dftB = [&](){ fft16B(); midtw(); xfft_dit4(z, Wt, lane); };

        // chain: v = e0; for l=5..0: v = D_l M F v.  (F#1 folded into init)
        Mstr(); Dstr(5);
        #pragma unroll 1
        for (int lp = 0; lp < 2; ++lp){
            dftB(); Mcon(); Dcon(4 - 2 * lp);   // barrier 1,3
            dftA(); Mstr(); Dstr(3 - 2 * lp);   // barrier 2,4
        }
        dftB(); Mcon(); Dcon(0);                // barrier 5
        // store a transposed into xb1: a[16*l + 4*wid + j] -> xb1[(4*wid+j)*64 + l]
        #pragma unroll
        for (int j = 0; j < 4; ++j) xb1[(4 * wid + j) * 64 + lane] = z[j];
        __syncthreads();                        // barrier 6
    } else {
        // waves 4-7: match the chain's 6 barriers
        #pragma unroll 1
        for (int i = 0; i < 6; ++i) __syncthreads();
    }

    // ================= dot phase: every wave its own row =================
    float re = 0.0f, im = 0.0f;
    #pragma unroll
    for (int i = 0; i < 4; ++i){
        float4 xv = xr[i];
        float xs[4] = {xv.x, xv.y, xv.z, xv.w};
        #pragma unroll
        for (int j = 0; j < 4; ++j){
            float2 av = xb1[(4 * i + j) * 64 + lane];   // a[16*lane + 4i + j]
            float x  = fminf(fmaxf(xs[j], -0.999f), 0.999f);
            float cc = sqrtf(fmaf(-x, x, 1.0f));
            re = fmaf(av.x, cc, re);  re = fmaf(-av.y, x,  re);
            im = fmaf(av.x, x,  im);  im = fmaf( av.y, cc, im);
        }
    }

    float2 s = make_float2(re, im);
    s = cadd(s, dpp2<DPP_XOR1>(s));
    s = cadd(s, dpp2<DPP_XOR2>(s));
    s = cadd(s, swz2<SWZ_XOR4>(s));
    s = cadd(s, dpp2<DPP_XOR8>(s));
    s = cadd(s, swz2<SWZ_XOR16>(s));
    s = cadd(s, p32_2(s, (lane & 32) != 0));

    if (lane == 0){
        out[row] = fmaf(s.y * rsqrtf(fmaf(s.x, s.x, s.y * s.y)), 0.5f, 0.5f);
    }
}

extern "C" void kernel_launch(void* const* d_in, const int* in_sizes, int n_in,
                              void* d_out, int out_size, void* d_ws, size_t ws_size,
                              hipStream_t stream) {
    const float* X = (const float*)d_in[0];   // [4096, 1024]
    const float* W = (const float*)d_in[1];   // [6*1024]
    float* out = (float*)d_out;               // [4096]
    (void)in_sizes; (void)n_in; (void)out_size; (void)d_ws; (void)ws_size;

    fused_kernel<<<4096 / 8, 512, 0, stream>>>(X, W, out);
}